// Round 3
// baseline (259.750 us; speedup 1.0000x reference)
//
#include <hip/hip_runtime.h>
#include <math.h>

// SpatialAttention n=4, c=128, hw=4096 fp32 in/out.
// R3: wave-independent fp16 MFMA flash attention.
//  - each wave owns 16 t: softmax fully in-wave (shfl), m/l in registers
//  - Q fragments in registers; one barrier/chunk via double-buffered sK/sV
//  - single fused prepass kernel (K^T*scale, Q^T, V->fp16)

#define HW 4096
#define CC 128
#define BS 64
#define KP 136   // sK pitch (halfs): 272 B rows, 16B-aligned
#define VPH 72   // sV / sPT pitch (halfs): 144 B rows, 16B-aligned

typedef _Float16 half8  __attribute__((ext_vector_type(8)));
typedef _Float16 half4v __attribute__((ext_vector_type(4)));
typedef _Float16 half2v __attribute__((ext_vector_type(2)));
typedef float    float4v __attribute__((ext_vector_type(4)));

// ---------- fused prepass: K^T*scale -> KT, Q^T -> QT, V -> fp16 ----------
__global__ __launch_bounds__(256)
void prepass(const float* __restrict__ K, const float* __restrict__ Q,
             const float* __restrict__ V, _Float16* __restrict__ KT,
             _Float16* __restrict__ QT, _Float16* __restrict__ Vh) {
  __shared__ float tile[32][65];
  const int bid = blockIdx.x;
  if (bid < 2048) {
    // transpose [b][128][4096] f32 -> [b][4096][128] f16 (K scaled by 1/sqrt(c))
    const bool isK = bid < 1024;
    const int id = bid & 1023;
    const float* in = isK ? K : Q;
    _Float16* out = isK ? KT : QT;
    const float scale = isK ? 0.08838834764831845f : 1.0f;
    const int c0 = (id & 3) << 5;
    const int s0 = ((id >> 2) & 63) << 6;
    const int b  = id >> 8;
    const float* ib = in + (size_t)b * CC * HW;
    _Float16* ob = out + (size_t)b * HW * CC;
    const int j  = threadIdx.x & 63;
    const int i0 = threadIdx.x >> 6;
    #pragma unroll
    for (int p = 0; p < 8; ++p) {
      const int i = p * 4 + i0;
      tile[i][j] = ib[(size_t)(c0 + i) * HW + s0 + j];
    }
    __syncthreads();
    const int j2 = threadIdx.x & 15;
    const int is = threadIdx.x >> 4;
    #pragma unroll
    for (int p = 0; p < 4; ++p) {
      const int s = p * 16 + is;
      half2v h;
      h.x = (_Float16)(tile[2 * j2][s] * scale);
      h.y = (_Float16)(tile[2 * j2 + 1][s] * scale);
      *(half2v*)&ob[(size_t)(s0 + s) * CC + c0 + 2 * j2] = h;
    }
  } else {
    const int id = bid - 2048;  // 2048 blocks, 4 f32 each
    const int base = (id * 256 + (int)threadIdx.x) * 4;
    const float4v v = *(const float4v*)(V + base);
    half4v h;
    h.x = (_Float16)v.x; h.y = (_Float16)v.y; h.z = (_Float16)v.z; h.w = (_Float16)v.w;
    *(half4v*)(Vh + base) = h;
  }
}

// ---------- main: wave-independent flash attention ----------
__global__ __launch_bounds__(256, 1)
void attn_mfma(const _Float16* __restrict__ KT, const _Float16* __restrict__ QT,
               const _Float16* __restrict__ Vh, float* __restrict__ Og) {
  __shared__ __align__(16) _Float16 sK[2][BS][KP];    // 34816 B  (K^T chunk [s][c], pre-scaled)
  __shared__ __align__(16) _Float16 sV[2][CC][VPH];   // 36864 B  (V chunk [e][s])
  __shared__ __align__(16) _Float16 sPT[4][16][VPH];  //  9216 B  (wave-private P^T [t][s])

  const int tid  = threadIdx.x;
  const int b    = blockIdx.x >> 6;
  const int tt0  = (blockIdx.x & 63) << 6;
  const int w    = tid >> 6;    // wave owns t in [tt0+16w, tt0+16w+16)
  const int lane = tid & 63;
  const int q    = lane >> 4;   // quad
  const int tc   = lane & 15;   // t within wave tile / m-index / n-index

  const _Float16* KTb = KT + (size_t)b * HW * CC;
  const _Float16* Vb  = Vh + (size_t)b * CC * HW;
  float* Ob = Og + (size_t)b * CC * HW;

  // Q B-fragments in registers (B[k=8q+j][n=tc] for each 32-wide k step)
  half8 qf[4];
  {
    const _Float16* qp = QT + (size_t)b * HW * CC + (size_t)(tt0 + 16 * w + tc) * CC + 8 * q;
    #pragma unroll
    for (int ks = 0; ks < 4; ++ks) qf[ks] = *(const half8*)(qp + 32 * ks);
  }

  // prefetch chunk 0 into registers
  uint4 rk[4], rv[4];
  #pragma unroll
  for (int p = 0; p < 4; ++p) {
    const int ln = p * 256 + tid;
    rk[p] = *(const uint4*)(KTb + (size_t)(ln >> 4) * CC + (ln & 15) * 8);
    rv[p] = *(const uint4*)(Vb + (size_t)(ln >> 3) * HW + (ln & 7) * 8);
  }

  float4v accO[8];
  #pragma unroll
  for (int it = 0; it < 8; ++it) accO[it] = (float4v){0.f, 0.f, 0.f, 0.f};
  float m_run = -1e30f, l_run = 0.0f;

  for (int s0 = 0; s0 < HW; s0 += BS) {
    const int buf = (s0 >> 6) & 1;

    // store staged chunk (loaded last iteration) into this buffer
    #pragma unroll
    for (int p = 0; p < 4; ++p) {
      const int ln = p * 256 + tid;
      *(uint4*)&sK[buf][ln >> 4][(ln & 15) * 8] = rk[p];
      *(uint4*)&sV[buf][ln >> 3][(ln & 7) * 8]  = rv[p];
    }
    __syncthreads();  // the only barrier per chunk (dbuf covers write/read overlap)

    // prefetch next chunk (consumed after next barrier)
    if (s0 + BS < HW) {
      const int s1 = s0 + BS;
      #pragma unroll
      for (int p = 0; p < 4; ++p) {
        const int ln = p * 256 + tid;
        rk[p] = *(const uint4*)(KTb + (size_t)(s1 + (ln >> 4)) * CC + (ln & 15) * 8);
        rv[p] = *(const uint4*)(Vb + (size_t)(ln >> 3) * HW + s1 + (ln & 7) * 8);
      }
    }

    // ---- QK: S[s][t] for 4 s-tiles x own 16 t ----
    float4v acc[4];
    #pragma unroll
    for (int j = 0; j < 4; ++j) acc[j] = (float4v){0.f, 0.f, 0.f, 0.f};
    #pragma unroll
    for (int ks = 0; ks < 4; ++ks) {
      #pragma unroll
      for (int j = 0; j < 4; ++j) {
        const half8 a = *(const half8*)&sK[buf][16 * j + tc][32 * ks + 8 * q];
        acc[j] = __builtin_amdgcn_mfma_f32_16x16x32_f16(a, qf[ks], acc[j], 0, 0, 0);
      }
    }

    // ---- in-wave online softmax (column t = tc; s spans quads x regs x tiles) ----
    float cm = -1e30f;
    #pragma unroll
    for (int j = 0; j < 4; ++j) {
      cm = fmaxf(cm, fmaxf(fmaxf(acc[j].x, acc[j].y), fmaxf(acc[j].z, acc[j].w)));
    }
    cm = fmaxf(cm, __shfl_xor(cm, 16));
    cm = fmaxf(cm, __shfl_xor(cm, 32));
    const float m_new = fmaxf(m_run, cm);
    const float alpha = __expf(m_run - m_new);
    float psum = 0.0f;
    #pragma unroll
    for (int j = 0; j < 4; ++j) {
      const float p0 = __expf(acc[j].x - m_new);
      const float p1 = __expf(acc[j].y - m_new);
      const float p2 = __expf(acc[j].z - m_new);
      const float p3 = __expf(acc[j].w - m_new);
      psum += (p0 + p1) + (p2 + p3);
      half4v h;
      h.x = (_Float16)p0; h.y = (_Float16)p1; h.z = (_Float16)p2; h.w = (_Float16)p3;
      *(half4v*)&sPT[w][tc][16 * j + 4 * q] = h;  // P^T[t][s], s = 16j+4q+r
    }
    psum += __shfl_xor(psum, 16);
    psum += __shfl_xor(psum, 32);
    l_run = l_run * alpha + psum;
    m_run = m_new;

    // ---- rescale O, then O[e][t] += V * P^T (wave-private, no barrier) ----
    #pragma unroll
    for (int it = 0; it < 8; ++it) {
      accO[it].x *= alpha; accO[it].y *= alpha; accO[it].z *= alpha; accO[it].w *= alpha;
    }
    #pragma unroll
    for (int ks = 0; ks < 2; ++ks) {
      const half8 bp = *(const half8*)&sPT[w][tc][32 * ks + 8 * q];
      #pragma unroll
      for (int it = 0; it < 8; ++it) {
        const half8 av = *(const half8*)&sV[buf][16 * it + tc][32 * ks + 8 * q];
        accO[it] = __builtin_amdgcn_mfma_f32_16x16x32_f16(av, bp, accO[it], 0, 0, 0);
      }
    }
  }

  // ---- epilogue: O /= l ----
  const float li = 1.0f / l_run;
  const int t = tt0 + 16 * w + tc;
  #pragma unroll
  for (int it = 0; it < 8; ++it) {
    const int e0 = 16 * it + 4 * q;
    Ob[(size_t)(e0 + 0) * HW + t] = accO[it].x * li;
    Ob[(size_t)(e0 + 1) * HW + t] = accO[it].y * li;
    Ob[(size_t)(e0 + 2) * HW + t] = accO[it].z * li;
    Ob[(size_t)(e0 + 3) * HW + t] = accO[it].w * li;
  }
}

extern "C" void kernel_launch(void* const* d_in, const int* in_sizes, int n_in,
                              void* d_out, int out_size, void* d_ws, size_t ws_size,
                              hipStream_t stream) {
  const float* key   = (const float*)d_in[0];
  const float* query = (const float*)d_in[1];
  const float* value = (const float*)d_in[2];
  float* out = (float*)d_out;

  const size_t TEN = (size_t)4 * HW * CC * sizeof(_Float16);  // 4 MiB per fp16 tensor
  _Float16* KT = (_Float16*)d_ws;
  _Float16* QT = (_Float16*)((char*)d_ws + TEN);
  _Float16* Vh = (_Float16*)((char*)d_ws + 2 * TEN);
  (void)ws_size;

  prepass<<<dim3(4096), dim3(256), 0, stream>>>(key, query, value, KT, QT, Vh);
  attn_mfma<<<dim3(256), dim3(256), 0, stream>>>(KT, QT, Vh, out);
}

// Round 4
// 231.894 us; speedup vs baseline: 1.1201x; 1.1201x over previous
//
#include <hip/hip_runtime.h>
#include <math.h>

// SpatialAttention n=4, c=128, hw=4096 fp32 in/out.
// R4: occupancy fix. 512-thr blocks (2 waves/SIMD). Wave-pair shares 16 t,
// each wave owns an s-half with private online-softmax state; single barrier
// per 128-s chunk (dbuf K/V); one exact (m,l,O) merge at the end.

#define HW 4096
#define CC 128
#define KP 136   // sK/sV row pitch (halfs): 272 B rows; b128 phases tile banks
#define PP 72    // sPT pitch

typedef _Float16 half8  __attribute__((ext_vector_type(8)));
typedef _Float16 half4v __attribute__((ext_vector_type(4)));
typedef float    float4v __attribute__((ext_vector_type(4)));

// ---------- prepass: K^T*scale -> KT, Q^T -> QT, V -> fp16 ----------
__global__ __launch_bounds__(256)
void prepass(const float* __restrict__ K, const float* __restrict__ Q,
             const float* __restrict__ V, _Float16* __restrict__ KT,
             _Float16* __restrict__ QT, _Float16* __restrict__ Vh) {
  __shared__ float tile[32][65];
  const int bid = blockIdx.x;
  if (bid < 2048) {
    const bool isK = bid < 1024;
    const int id = bid & 1023;
    const float* in = isK ? K : Q;
    _Float16* out = isK ? KT : QT;
    const float scale = isK ? 0.08838834764831845f : 1.0f;
    const int c0 = (id & 3) << 5;
    const int s0 = ((id >> 2) & 63) << 6;
    const int b  = id >> 8;
    const float* ib = in + (size_t)b * CC * HW;
    _Float16* ob = out + (size_t)b * HW * CC;
    const int j  = threadIdx.x & 63;
    const int i0 = threadIdx.x >> 6;
    #pragma unroll
    for (int p = 0; p < 8; ++p) {
      const int i = p * 4 + i0;
      tile[i][j] = ib[(size_t)(c0 + i) * HW + s0 + j];
    }
    __syncthreads();
    // write half8 per thread: s = tid>>2, c-block j3 = tid&3
    const int s  = threadIdx.x >> 2;
    const int j3 = threadIdx.x & 3;
    half8 h;
    #pragma unroll
    for (int k = 0; k < 8; ++k) h[k] = (_Float16)(tile[8 * j3 + k][s] * scale);
    *(half8*)&ob[(size_t)(s0 + s) * CC + c0 + 8 * j3] = h;
  } else {
    const int id = bid - 2048;
    const int base = (id * 256 + (int)threadIdx.x) * 4;
    const float4v v = *(const float4v*)(V + base);
    half4v h;
    h.x = (_Float16)v.x; h.y = (_Float16)v.y; h.z = (_Float16)v.z; h.w = (_Float16)v.w;
    *(half4v*)(Vh + base) = h;
  }
}

// ---------- main: 8 waves, wave-private flash state, end merge ----------
__global__ __launch_bounds__(512, 2)
void attn_mfma(const _Float16* __restrict__ KT, const _Float16* __restrict__ QT,
               const _Float16* __restrict__ Vh, float* __restrict__ Og) {
  __shared__ __align__(16) _Float16 sK[2][128][KP];   // 69632 B  K^T chunk [s][c]
  __shared__ __align__(16) _Float16 sV[2][128][KP];   // 69632 B  V chunk [e][s]
  __shared__ __align__(16) _Float16 sPT[8][16][PP];   // 18432 B  wave-private P^T
  __shared__ float sMm[8][16], sMl[8][16];            //  1024 B

  const int tid  = threadIdx.x;
  const int b    = blockIdx.x >> 6;
  const int tt0  = (blockIdx.x & 63) << 6;
  const int w    = tid >> 6;        // 8 waves
  const int pair = w >> 1;          // t-group: t in [tt0+16*pair, +16)
  const int par  = w & 1;           // s-half within each 128-chunk
  const int lane = tid & 63;
  const int q    = lane >> 4;
  const int tc   = lane & 15;
  const int spar = 64 * par;

  const _Float16* KTb = KT + (size_t)b * HW * CC;
  const _Float16* Vb  = Vh + (size_t)b * CC * HW;
  float* Ob = Og + (size_t)b * CC * HW;

  // Q B-fragments in registers
  half8 qf[4];
  {
    const _Float16* qp = QT + (size_t)b * HW * CC + (size_t)(tt0 + 16 * pair + tc) * CC + 8 * q;
    #pragma unroll
    for (int ks = 0; ks < 4; ++ks) qf[ks] = *(const half8*)(qp + 32 * ks);
  }

  // prefetch chunk 0 (128 s x 128 c fp16 = 32 KB each for K and V; 512 thr x 4 uint4)
  uint4 rk[4], rv[4];
  #pragma unroll
  for (int p = 0; p < 4; ++p) {
    const int ln = p * 512 + tid;
    rk[p] = *(const uint4*)(KTb + (size_t)(ln >> 4) * CC + (ln & 15) * 8);
    rv[p] = *(const uint4*)(Vb + (size_t)(ln >> 4) * HW + (ln & 15) * 8);
  }

  float4v accO[8];
  #pragma unroll
  for (int it = 0; it < 8; ++it) accO[it] = (float4v){0.f, 0.f, 0.f, 0.f};
  float m_run = -1e30f, l_run = 0.0f;

  for (int it = 0; it < HW / 128; ++it) {
    const int buf = it & 1;
    const int s0 = it * 128;

    #pragma unroll
    for (int p = 0; p < 4; ++p) {
      const int ln = p * 512 + tid;
      *(uint4*)&sK[buf][ln >> 4][(ln & 15) * 8] = rk[p];
      *(uint4*)&sV[buf][ln >> 4][(ln & 15) * 8] = rv[p];
    }
    __syncthreads();  // only barrier per chunk (dbuf)

    if (s0 + 128 < HW) {
      const int s1 = s0 + 128;
      #pragma unroll
      for (int p = 0; p < 4; ++p) {
        const int ln = p * 512 + tid;
        rk[p] = *(const uint4*)(KTb + (size_t)(s1 + (ln >> 4)) * CC + (ln & 15) * 8);
        rv[p] = *(const uint4*)(Vb + (size_t)(ln >> 4) * HW + s1 + (ln & 15) * 8);
      }
    }

    // ---- QK: S[s][t], own 64-s half x own 16 t ----
    float4v acc[4];
    #pragma unroll
    for (int j = 0; j < 4; ++j) acc[j] = (float4v){0.f, 0.f, 0.f, 0.f};
    #pragma unroll
    for (int ks = 0; ks < 4; ++ks) {
      #pragma unroll
      for (int j = 0; j < 4; ++j) {
        const half8 a = *(const half8*)&sK[buf][spar + 16 * j + tc][32 * ks + 8 * q];
        acc[j] = __builtin_amdgcn_mfma_f32_16x16x32_f16(a, qf[ks], acc[j], 0, 0, 0);
      }
    }

    // ---- in-wave online softmax (private state) ----
    float cm = -1e30f;
    #pragma unroll
    for (int j = 0; j < 4; ++j)
      cm = fmaxf(cm, fmaxf(fmaxf(acc[j].x, acc[j].y), fmaxf(acc[j].z, acc[j].w)));
    cm = fmaxf(cm, __shfl_xor(cm, 16));
    cm = fmaxf(cm, __shfl_xor(cm, 32));
    const float m_new = fmaxf(m_run, cm);
    const float alpha = __expf(m_run - m_new);
    float psum = 0.0f;
    #pragma unroll
    for (int j = 0; j < 4; ++j) {
      const float p0 = __expf(acc[j].x - m_new);
      const float p1 = __expf(acc[j].y - m_new);
      const float p2 = __expf(acc[j].z - m_new);
      const float p3 = __expf(acc[j].w - m_new);
      psum += (p0 + p1) + (p2 + p3);
      half4v h;
      h.x = (_Float16)p0; h.y = (_Float16)p1; h.z = (_Float16)p2; h.w = (_Float16)p3;
      *(half4v*)&sPT[w][tc][16 * j + 4 * q] = h;  // s_loc = 16j+4q+r
    }
    psum += __shfl_xor(psum, 16);
    psum += __shfl_xor(psum, 32);
    l_run = l_run * alpha + psum;
    m_run = m_new;

    // ---- PV: O[e][t] += V_half * P^T (wave-private) ----
    #pragma unroll
    for (int i2 = 0; i2 < 8; ++i2) {
      accO[i2].x *= alpha; accO[i2].y *= alpha; accO[i2].z *= alpha; accO[i2].w *= alpha;
    }
    #pragma unroll
    for (int ks = 0; ks < 2; ++ks) {
      const half8 bp = *(const half8*)&sPT[w][tc][32 * ks + 8 * q];
      #pragma unroll
      for (int i2 = 0; i2 < 8; ++i2) {
        const half8 av = *(const half8*)&sV[buf][16 * i2 + tc][spar + 32 * ks + 8 * q];
        accO[i2] = __builtin_amdgcn_mfma_f32_16x16x32_f16(av, bp, accO[i2], 0, 0, 0);
      }
    }
  }

  // ---- end merge of the wave-pair's two partial states ----
  float* mergeO = (float*)&sK[0][0][0];  // [4][16][132] floats = 33792 B (sK dead)
  __syncthreads();
  if (lane < 16) { sMm[w][tc] = m_run; sMl[w][tc] = l_run; }
  __syncthreads();
  const float m_oth = sMm[w ^ 1][tc];
  const float M     = fmaxf(m_run, m_oth);
  const float a     = __expf(m_run - M);
  const float lp    = l_run * a;
  #pragma unroll
  for (int i2 = 0; i2 < 8; ++i2) {
    accO[i2].x *= a; accO[i2].y *= a; accO[i2].z *= a; accO[i2].w *= a;
  }
  if (par == 1) {
    #pragma unroll
    for (int i2 = 0; i2 < 8; ++i2)
      *(float4v*)&mergeO[(size_t)pair * 2112 + tc * 132 + 16 * i2 + 4 * q] = accO[i2];
    if (lane < 16) sMl[w][tc] = lp;
  }
  __syncthreads();
  if (par == 0) {
    const float l_tot = lp + sMl[w ^ 1][tc];
    const float li = 1.0f / l_tot;
    const int t = tt0 + 16 * pair + tc;
    #pragma unroll
    for (int i2 = 0; i2 < 8; ++i2) {
      const float4v o = *(const float4v*)&mergeO[(size_t)pair * 2112 + tc * 132 + 16 * i2 + 4 * q];
      const int e0 = 16 * i2 + 4 * q;
      Ob[(size_t)(e0 + 0) * HW + t] = (accO[i2].x + o.x) * li;
      Ob[(size_t)(e0 + 1) * HW + t] = (accO[i2].y + o.y) * li;
      Ob[(size_t)(e0 + 2) * HW + t] = (accO[i2].z + o.z) * li;
      Ob[(size_t)(e0 + 3) * HW + t] = (accO[i2].w + o.w) * li;
    }
  }
}

extern "C" void kernel_launch(void* const* d_in, const int* in_sizes, int n_in,
                              void* d_out, int out_size, void* d_ws, size_t ws_size,
                              hipStream_t stream) {
  const float* key   = (const float*)d_in[0];
  const float* query = (const float*)d_in[1];
  const float* value = (const float*)d_in[2];
  float* out = (float*)d_out;

  const size_t TEN = (size_t)4 * HW * CC * sizeof(_Float16);  // 4 MiB per fp16 tensor
  _Float16* KT = (_Float16*)d_ws;
  _Float16* QT = (_Float16*)((char*)d_ws + TEN);
  _Float16* Vh = (_Float16*)((char*)d_ws + 2 * TEN);
  (void)ws_size;

  prepass<<<dim3(4096), dim3(256), 0, stream>>>(key, query, value, KT, QT, Vh);
  attn_mfma<<<dim3(256), dim3(512), 0, stream>>>(KT, QT, Vh, out);
}

// Round 5
// 134.460 us; speedup vs baseline: 1.9318x; 1.7246x over previous
//
#include <hip/hip_runtime.h>
#include <math.h>

// SpatialAttention n=4, c=128, hw=4096 fp32 in/out.
// R5: async-DMA staging (global_load_lds w16, XOR-swizzled LDS, no staging regs
// -> kills R4's scratch spill), 1024-thr blocks (4 waves/SIMD). Wave = (t-group,
// s-slot): 16t x 32s private flash state, 1 barrier/chunk, exact 4-way end merge.

#define HW 4096
#define CC 128

typedef _Float16 half8  __attribute__((ext_vector_type(8)));
typedef _Float16 half4v __attribute__((ext_vector_type(4)));
typedef float    float4v __attribute__((ext_vector_type(4)));

__device__ __forceinline__ void async_copy16(void* lds, const void* g) {
  __builtin_amdgcn_global_load_lds(
      (const __attribute__((address_space(1))) unsigned int*)g,
      (__attribute__((address_space(3))) unsigned int*)lds, 16, 0, 0);
}

// ---------- prepass: K^T*scale -> KT, Q^T -> QT, V -> fp16 ----------
__global__ __launch_bounds__(256)
void prepass(const float* __restrict__ K, const float* __restrict__ Q,
             const float* __restrict__ V, _Float16* __restrict__ KT,
             _Float16* __restrict__ QT, _Float16* __restrict__ Vh) {
  const int bid = blockIdx.x;
  const int tid = threadIdx.x;
  if (bid < 2048) {
    __shared__ float tile[32][65];
    const bool isK = bid < 1024;
    const int id = bid & 1023;
    const float* in = isK ? K : Q;
    _Float16* out = isK ? KT : QT;
    const float scale = isK ? 0.08838834764831845f : 1.0f;
    const int c0 = (id & 3) << 5;
    const int s0 = ((id >> 2) & 63) << 6;
    const int b  = id >> 8;
    const float* ib = in + (size_t)b * CC * HW;
    _Float16* ob = out + (size_t)b * HW * CC;
    const int r  = tid >> 4;
    const int c4 = (tid & 15) * 4;
    *(float4*)&tile[r][c4]      = *(const float4*)(ib + (size_t)(c0 + r) * HW + s0 + c4);
    *(float4*)&tile[r + 16][c4] = *(const float4*)(ib + (size_t)(c0 + r + 16) * HW + s0 + c4);
    __syncthreads();
    const int s  = tid >> 2;
    const int c8 = (tid & 3) * 8;
    half8 h;
    #pragma unroll
    for (int k = 0; k < 8; ++k) h[k] = (_Float16)(tile[c8 + k][s] * scale);
    *(half8*)&ob[(size_t)(s0 + s) * CC + c0 + c8] = h;
  } else {
    const int id = bid - 2048;  // 512 blocks x 256 thr x 4 float4 = all of V
    #pragma unroll
    for (int p = 0; p < 4; ++p) {
      const int f = id * 1024 + p * 256 + tid;
      const float4v v = *(const float4v*)(V + 4 * (size_t)f);
      half4v h;
      h.x = (_Float16)v.x; h.y = (_Float16)v.y; h.z = (_Float16)v.z; h.w = (_Float16)v.w;
      *(half4v*)(Vh + 4 * (size_t)f) = h;
    }
  }
}

// ---------- main: 16 waves, async-DMA dbuf staging, private flash state ----------
__global__ __launch_bounds__(1024, 4)
void attn_mfma(const _Float16* __restrict__ KT, const _Float16* __restrict__ QT,
               const _Float16* __restrict__ Vh, float* __restrict__ Og) {
  __shared__ __align__(16) _Float16 sK[2][128][CC];   // 65536 B, swizzled K^T chunk [s][c]
  __shared__ __align__(16) _Float16 sV[2][128][CC];   // 65536 B, swizzled V chunk [e][s]
  __shared__ __align__(16) _Float16 sPT[16][16][40];  // 20480 B, wave-private P^T
  __shared__ float sMm[16][16], sMl[16][16];          //  2048 B

  const int tid  = threadIdx.x;
  const int b    = blockIdx.x >> 6;
  const int tt0  = (blockIdx.x & 63) << 6;
  const int w    = tid >> 6;    // 16 waves
  const int lane = tid & 63;
  const int q    = lane >> 4;
  const int tc   = lane & 15;
  const int g    = w >> 2;      // t-group: t in [tt0+16g, +16)
  const int sl   = w & 3;       // s-slot: s_loc in [32sl, 32sl+32)

  const _Float16* KTb = KT + (size_t)b * HW * CC;
  const _Float16* Vb  = Vh + (size_t)b * CC * HW;
  float* Ob = Og + (size_t)b * CC * HW;

  // Q B-fragments in registers
  half8 qf[4];
  {
    const _Float16* qp = QT + (size_t)b * HW * CC + (size_t)(tt0 + 16 * g + tc) * CC + 8 * q;
    #pragma unroll
    for (int ks = 0; ks < 4; ++ks) qf[ks] = *(const half8*)(qp + 32 * ks);
  }

  // async stage of chunk sn into buffer buf: 16 waves x 2 instr x (K,V)
  const int r0    = w * 8;
  const int lrow  = lane >> 4;           // 0..3
  const int lchnk = lane & 15;           // 16B chunk 0..15
  #define STAGE(sn, buf)                                                           \
    {                                                                              \
      _Pragma("unroll")                                                            \
      for (int p = 0; p < 2; ++p) {                                                \
        const int row = r0 + p * 4 + lrow;                                         \
        const int gc  = lchnk ^ (row & 15);                                        \
        async_copy16(&sK[buf][r0 + p * 4][0],                                      \
                     KTb + (size_t)((sn) + row) * CC + gc * 8);                    \
        async_copy16(&sV[buf][r0 + p * 4][0],                                      \
                     Vb + (size_t)row * HW + (sn) + gc * 8);                       \
      }                                                                            \
    }

  STAGE(0, 0);

  float4v accO[8];
  #pragma unroll
  for (int i2 = 0; i2 < 8; ++i2) accO[i2] = (float4v){0.f, 0.f, 0.f, 0.f};
  float m_run = -1e30f, l_run = 0.0f;

  __syncthreads();  // drains the chunk-0 DMA (vmcnt before s_barrier)

  for (int it = 0; it < HW / 128; ++it) {
    const int buf = it & 1;
    if (it + 1 < HW / 128) STAGE((it + 1) * 128, buf ^ 1);  // in flight during compute

    // ---- QK: S for own 32 s x own 16 t ----
    float4v acc[2];
    acc[0] = (float4v){0.f, 0.f, 0.f, 0.f};
    acc[1] = (float4v){0.f, 0.f, 0.f, 0.f};
    #pragma unroll
    for (int ks = 0; ks < 4; ++ks) {
      #pragma unroll
      for (int j = 0; j < 2; ++j) {
        const int row = 32 * sl + 16 * j + tc;
        const half8 a = *(const half8*)&sK[buf][row][((4 * ks + q) ^ tc) * 8];
        acc[j] = __builtin_amdgcn_mfma_f32_16x16x32_f16(a, qf[ks], acc[j], 0, 0, 0);
      }
    }

    // ---- in-wave online softmax (private state, 8 vals/lane) ----
    float cm = -1e30f;
    #pragma unroll
    for (int j = 0; j < 2; ++j)
      cm = fmaxf(cm, fmaxf(fmaxf(acc[j].x, acc[j].y), fmaxf(acc[j].z, acc[j].w)));
    cm = fmaxf(cm, __shfl_xor(cm, 16));
    cm = fmaxf(cm, __shfl_xor(cm, 32));
    const float m_new = fmaxf(m_run, cm);
    const float alpha = __expf(m_run - m_new);
    float psum = 0.0f;
    #pragma unroll
    for (int j = 0; j < 2; ++j) {
      const float p0 = __expf(acc[j].x - m_new);
      const float p1 = __expf(acc[j].y - m_new);
      const float p2 = __expf(acc[j].z - m_new);
      const float p3 = __expf(acc[j].w - m_new);
      psum += (p0 + p1) + (p2 + p3);
      half4v h;
      h.x = (_Float16)p0; h.y = (_Float16)p1; h.z = (_Float16)p2; h.w = (_Float16)p3;
      *(half4v*)&sPT[w][tc][16 * j + 4 * q] = h;  // s_loc = 16j+4q+r
    }
    psum += __shfl_xor(psum, 16);
    psum += __shfl_xor(psum, 32);
    l_run = l_run * alpha + psum;
    m_run = m_new;

    // ---- PV: O[e][t] += V[:, own 32 s] * P^T ----
    #pragma unroll
    for (int i2 = 0; i2 < 8; ++i2) {
      accO[i2].x *= alpha; accO[i2].y *= alpha; accO[i2].z *= alpha; accO[i2].w *= alpha;
    }
    const half8 bp = *(const half8*)&sPT[w][tc][8 * q];
    #pragma unroll
    for (int i2 = 0; i2 < 8; ++i2) {
      const half8 av = *(const half8*)&sV[buf][16 * i2 + tc][((4 * sl + q) ^ tc) * 8];
      accO[i2] = __builtin_amdgcn_mfma_f32_16x16x32_f16(av, bp, accO[i2], 0, 0, 0);
    }

    __syncthreads();  // only barrier/chunk: drains next-chunk DMA + guards dbuf
  }

  // ---- exact 4-way merge per t-group ----
  if (lane < 16) { sMm[w][tc] = m_run; sMl[w][tc] = l_run; }
  __syncthreads();
  const float M = fmaxf(fmaxf(sMm[4 * g + 0][tc], sMm[4 * g + 1][tc]),
                        fmaxf(sMm[4 * g + 2][tc], sMm[4 * g + 3][tc]));
  const float aa = __expf(m_run - M);
  #pragma unroll
  for (int i2 = 0; i2 < 8; ++i2) {
    accO[i2].x *= aa; accO[i2].y *= aa; accO[i2].z *= aa; accO[i2].w *= aa;
  }
  if (lane < 16) sMl[w][tc] = l_run * aa;  // lp (raw l no longer needed)

  float* mbuf = (float*)&sK[0][0][0];  // [4][16][128] f32 = 32768 B, aliases sK[0] (dead)
  for (int r = 1; r < 4; ++r) {
    __syncthreads();
    if (sl == r) {
      #pragma unroll
      for (int i2 = 0; i2 < 8; ++i2) {
        const int c4s = (4 * i2 + q) ^ ((tc & 7) << 2);
        *(float4v*)&mbuf[g * 2048 + tc * 128 + 4 * c4s] = accO[i2];
      }
    }
    __syncthreads();
    if (sl == 0) {
      #pragma unroll
      for (int i2 = 0; i2 < 8; ++i2) {
        const int c4s = (4 * i2 + q) ^ ((tc & 7) << 2);
        const float4v o = *(const float4v*)&mbuf[g * 2048 + tc * 128 + 4 * c4s];
        accO[i2].x += o.x; accO[i2].y += o.y; accO[i2].z += o.z; accO[i2].w += o.w;
      }
    }
  }

  if (sl == 0) {
    const float lt = (sMl[4 * g + 0][tc] + sMl[4 * g + 1][tc]) +
                     (sMl[4 * g + 2][tc] + sMl[4 * g + 3][tc]);
    const float li = 1.0f / lt;
    const int t = tt0 + 16 * g + tc;
    #pragma unroll
    for (int i2 = 0; i2 < 8; ++i2) {
      const int e0 = 16 * i2 + 4 * q;
      Ob[(size_t)(e0 + 0) * HW + t] = accO[i2].x * li;
      Ob[(size_t)(e0 + 1) * HW + t] = accO[i2].y * li;
      Ob[(size_t)(e0 + 2) * HW + t] = accO[i2].z * li;
      Ob[(size_t)(e0 + 3) * HW + t] = accO[i2].w * li;
    }
  }
}

extern "C" void kernel_launch(void* const* d_in, const int* in_sizes, int n_in,
                              void* d_out, int out_size, void* d_ws, size_t ws_size,
                              hipStream_t stream) {
  const float* key   = (const float*)d_in[0];
  const float* query = (const float*)d_in[1];
  const float* value = (const float*)d_in[2];
  float* out = (float*)d_out;

  const size_t TEN = (size_t)4 * HW * CC * sizeof(_Float16);  // 4 MiB per fp16 tensor
  _Float16* KT = (_Float16*)d_ws;
  _Float16* QT = (_Float16*)((char*)d_ws + TEN);
  _Float16* Vh = (_Float16*)((char*)d_ws + 2 * TEN);
  (void)ws_size;

  prepass<<<dim3(2560), dim3(256), 0, stream>>>(key, query, value, KT, QT, Vh);
  attn_mfma<<<dim3(256), dim3(1024), 0, stream>>>(KT, QT, Vh, out);
}